// Round 1
// baseline (160.942 us; speedup 1.0000x reference)
//
#include <hip/hip_runtime.h>
#include <hip/hip_bf16.h>

// sqrt(1/(2*0.3^2*ln2)) : fold exp scale into coordinates so
// phi = exp2(-sum((x*s - c*s)^2))
#define SCALE 2.8310728f
#define CHUNKS 4

typedef float f2 __attribute__((ext_vector_type(2)));

// Pack per-center data as two float4s: [cx*s, cy*s, cz*s, 0][cu, cv, cw, 0]
// so the hot loop does 2 x dwordx4 broadcast loads per center.
__global__ void rbf_prep_kernel(const float* __restrict__ centers,
                                const float* __restrict__ cu,
                                const float* __restrict__ cv,
                                const float* __restrict__ cw,
                                float4* __restrict__ cpack, int M) {
    int m = blockIdx.x * 256 + threadIdx.x;
    if (m < M) {
        float4 a, b;
        a.x = centers[3 * m + 0] * SCALE;
        a.y = centers[3 * m + 1] * SCALE;
        a.z = centers[3 * m + 2] * SCALE;
        a.w = 0.f;
        b.x = cu[m];
        b.y = cv[m];
        b.z = cw[m];
        b.w = 0.f;
        cpack[2 * m + 0] = a;
        cpack[2 * m + 1] = b;
    }
}

// Block = 256 threads = 4 waves. Each block owns 128 points (2 per lane,
// packed in float2 halves to encourage v_pk_* fp32 ops). Each wave handles a
// distinct quarter of the centers; 4-way reduction through LDS at the end.
__global__ __launch_bounds__(256) void rbf_main_kernel(
    const float* __restrict__ x, const float4* __restrict__ cpack,
    float* __restrict__ out, int N, int M) {
    __shared__ float acc[CHUNKS][128][3];

    const int tid = threadIdx.x;
    const int lane = tid & 63;
    const int chunk = __builtin_amdgcn_readfirstlane(tid >> 6);  // wave-uniform
    const int pbase = blockIdx.x * 128;
    const int p0 = pbase + lane;
    const int p1 = pbase + 64 + lane;

    // Load the two points this lane owns (invalid -> 0, writes are guarded).
    float x00 = 0.f, x01 = 0.f, x02 = 0.f;
    float x10 = 0.f, x11 = 0.f, x12 = 0.f;
    if (p0 < N) {
        x00 = x[3 * p0 + 0];
        x01 = x[3 * p0 + 1];
        x02 = x[3 * p0 + 2];
    }
    if (p1 < N) {
        x10 = x[3 * p1 + 0];
        x11 = x[3 * p1 + 1];
        x12 = x[3 * p1 + 2];
    }

    const f2 X = {x00 * SCALE, x10 * SCALE};
    const f2 Y = {x01 * SCALE, x11 * SCALE};
    const f2 Z = {x02 * SCALE, x12 * SCALE};

    const int per = (M + CHUNKS - 1) / CHUNKS;
    const int jb = chunk * per;
    const int je = min(jb + per, M);

    f2 au = {0.f, 0.f}, av = {0.f, 0.f}, aw = {0.f, 0.f};

#pragma unroll 4
    for (int j = jb; j < je; ++j) {
        const float4 a = cpack[2 * j + 0];   // scaled center coords (broadcast)
        const float4 b = cpack[2 * j + 1];   // coeffs u,v,w (broadcast)
        f2 dx = X - a.x;
        f2 dy = Y - a.y;
        f2 dz = Z - a.z;
        f2 q = dx * dx;
        q += dy * dy;
        q += dz * dz;
        f2 phi;
        phi.x = __builtin_amdgcn_exp2f(-q.x);
        phi.y = __builtin_amdgcn_exp2f(-q.y);
        au += phi * b.x;
        av += phi * b.y;
        aw += phi * b.z;
    }

    // Fold the base field x*(1-||x||) into chunk 0's partial sums.
    if (chunk == 0) {
        float r0 = sqrtf(x00 * x00 + x01 * x01 + x02 * x02);
        float g0 = 1.f - r0;
        au.x += x00 * g0;
        av.x += x01 * g0;
        aw.x += x02 * g0;
        float r1 = sqrtf(x10 * x10 + x11 * x11 + x12 * x12);
        float g1 = 1.f - r1;
        au.y += x10 * g1;
        av.y += x11 * g1;
        aw.y += x12 * g1;
    }

    acc[chunk][lane][0] = au.x;
    acc[chunk][lane][1] = av.x;
    acc[chunk][lane][2] = aw.x;
    acc[chunk][64 + lane][0] = au.y;
    acc[chunk][64 + lane][1] = av.y;
    acc[chunk][64 + lane][2] = aw.y;
    __syncthreads();

    // 384 output floats per block; coalesced write.
    const int out_n = 3 * N;
#pragma unroll
    for (int e = tid; e < 384; e += 256) {
        int gi = pbase * 3 + e;
        if (gi < out_n) {
            int pl = e / 3;
            int c = e % 3;
            out[gi] = acc[0][pl][c] + acc[1][pl][c] + acc[2][pl][c] +
                      acc[3][pl][c];
        }
    }
}

extern "C" void kernel_launch(void* const* d_in, const int* in_sizes, int n_in,
                              void* d_out, int out_size, void* d_ws,
                              size_t ws_size, hipStream_t stream) {
    const float* x = (const float*)d_in[0];
    const float* centers = (const float*)d_in[1];
    const float* cu = (const float*)d_in[2];
    const float* cv = (const float*)d_in[3];
    const float* cw = (const float*)d_in[4];
    const int N = in_sizes[0] / 3;
    const int M = in_sizes[1] / 3;
    float4* cpack = (float4*)d_ws;
    float* out = (float*)d_out;

    hipLaunchKernelGGL(rbf_prep_kernel, dim3((M + 255) / 256), dim3(256), 0,
                       stream, centers, cu, cv, cw, cpack, M);
    hipLaunchKernelGGL(rbf_main_kernel, dim3((N + 127) / 128), dim3(256), 0,
                       stream, x, cpack, out, N, M);
}

// Round 2
// 139.510 us; speedup vs baseline: 1.1536x; 1.1536x over previous
//
#include <hip/hip_runtime.h>
#include <hip/hip_bf16.h>

// phi = exp(-d2/(2*ls^2)) = exp2(-s2*d2), s2 = 1/(2*ls^2*ln2) = 8.014973
// Expanded: exp2(2*s2*(x.c) - s2*|x|^2 - s2*|c|^2)
//   per-center pack a = (K2*cx, K2*cy, K2*cz, -S2*|c|^2), K2 = 2*S2
//   per-lane PX = -S2*|x|^2
#define S2 8.014973f
#define K2 16.029946f
#define CHUNKS 8   // 8 waves/block, each owns M/8 centers

typedef float f2 __attribute__((ext_vector_type(2)));

__global__ void rbf_prep_kernel(const float* __restrict__ centers,
                                const float* __restrict__ cu,
                                const float* __restrict__ cv,
                                const float* __restrict__ cw,
                                float4* __restrict__ cpack, int M) {
    int m = blockIdx.x * 256 + threadIdx.x;
    if (m < M) {
        float cx = centers[3 * m + 0];
        float cy = centers[3 * m + 1];
        float cz = centers[3 * m + 2];
        float4 a, b;
        a.x = K2 * cx;
        a.y = K2 * cy;
        a.z = K2 * cz;
        a.w = -S2 * (cx * cx + cy * cy + cz * cz);
        b.x = cu[m];
        b.y = cv[m];
        b.z = cw[m];
        b.w = 0.f;
        cpack[2 * m + 0] = a;
        cpack[2 * m + 1] = b;
    }
}

// Block = 512 threads = 8 waves; block owns 128 points (2/lane as f2 halves
// for v_pk_* fp32). Each wave handles a distinct 1/8 of the centers (j is
// wave-uniform -> scalar loads of cpack); 8-way LDS reduction at the end.
// grid = 782 blocks * 8 waves = 6256 waves (~76% occupancy ceiling) vs R1's
// 3128 (25% measured) -- R1 was grid-starved.
__global__ __launch_bounds__(512) void rbf_main_kernel(
    const float* __restrict__ x, const float4* __restrict__ cpack,
    float* __restrict__ out, int N, int M) {
    __shared__ float acc[CHUNKS][128][3];

    const int tid = threadIdx.x;
    const int lane = tid & 63;
    const int chunk = __builtin_amdgcn_readfirstlane(tid >> 6);  // wave-uniform
    const int pbase = blockIdx.x * 128;
    const int p0 = pbase + lane;
    const int p1 = pbase + 64 + lane;

    float x00 = 0.f, x01 = 0.f, x02 = 0.f;
    float x10 = 0.f, x11 = 0.f, x12 = 0.f;
    if (p0 < N) {
        x00 = x[3 * p0 + 0];
        x01 = x[3 * p0 + 1];
        x02 = x[3 * p0 + 2];
    }
    if (p1 < N) {
        x10 = x[3 * p1 + 0];
        x11 = x[3 * p1 + 1];
        x12 = x[3 * p1 + 2];
    }

    const f2 X = {x00, x10};
    const f2 Y = {x01, x11};
    const f2 Z = {x02, x12};
    const f2 PX = {-S2 * (x00 * x00 + x01 * x01 + x02 * x02),
                   -S2 * (x10 * x10 + x11 * x11 + x12 * x12)};

    const int per = (M + CHUNKS - 1) / CHUNKS;
    const int jb = chunk * per;
    const int je = min(jb + per, M);

    f2 au = {0.f, 0.f}, av = {0.f, 0.f}, aw = {0.f, 0.f};

#pragma unroll 4
    for (int j = jb; j < je; ++j) {
        const float4 a = cpack[2 * j + 0];  // uniform addr -> scalar load
        const float4 b = cpack[2 * j + 1];
        f2 e = PX + a.w;
        e += Z * a.z;
        e += Y * a.y;
        e += X * a.x;
        f2 phi;
        phi.x = __builtin_amdgcn_exp2f(e.x);
        phi.y = __builtin_amdgcn_exp2f(e.y);
        au += phi * b.x;
        av += phi * b.y;
        aw += phi * b.z;
    }

    // Fold base field x*(1-||x||) into chunk 0's partials.
    if (chunk == 0) {
        float g0 = 1.f - sqrtf(x00 * x00 + x01 * x01 + x02 * x02);
        au.x += x00 * g0;
        av.x += x01 * g0;
        aw.x += x02 * g0;
        float g1 = 1.f - sqrtf(x10 * x10 + x11 * x11 + x12 * x12);
        au.y += x10 * g1;
        av.y += x11 * g1;
        aw.y += x12 * g1;
    }

    acc[chunk][lane][0] = au.x;
    acc[chunk][lane][1] = av.x;
    acc[chunk][lane][2] = aw.x;
    acc[chunk][64 + lane][0] = au.y;
    acc[chunk][64 + lane][1] = av.y;
    acc[chunk][64 + lane][2] = aw.y;
    __syncthreads();

    const int out_n = 3 * N;
    if (tid < 384) {
        int gi = pbase * 3 + tid;
        if (gi < out_n) {
            int pl = tid / 3;
            int c = tid % 3;
            float s = 0.f;
#pragma unroll
            for (int k = 0; k < CHUNKS; ++k) s += acc[k][pl][c];
            out[gi] = s;
        }
    }
}

extern "C" void kernel_launch(void* const* d_in, const int* in_sizes, int n_in,
                              void* d_out, int out_size, void* d_ws,
                              size_t ws_size, hipStream_t stream) {
    const float* x = (const float*)d_in[0];
    const float* centers = (const float*)d_in[1];
    const float* cu = (const float*)d_in[2];
    const float* cv = (const float*)d_in[3];
    const float* cw = (const float*)d_in[4];
    const int N = in_sizes[0] / 3;
    const int M = in_sizes[1] / 3;
    float4* cpack = (float4*)d_ws;
    float* out = (float*)d_out;

    hipLaunchKernelGGL(rbf_prep_kernel, dim3((M + 255) / 256), dim3(256), 0,
                       stream, centers, cu, cv, cw, cpack, M);
    hipLaunchKernelGGL(rbf_main_kernel, dim3((N + 127) / 128), dim3(512), 0,
                       stream, x, cpack, out, N, M);
}